// Round 2
// baseline (210.719 us; speedup 1.0000x reference)
//
#include <hip/hip_runtime.h>
#include <stdint.h>

#define BATCH 16
#define CIN   64
#define COUT  64
#define NBR   8
#define HH    128
#define WW    128
#define HP    130           // padded H/W for x_t

typedef __attribute__((ext_vector_type(8)))  short short8;
typedef __attribute__((ext_vector_type(16))) float f32x16;

__device__ __forceinline__ unsigned short f2bf(float f) {
    union { float f; uint32_t u; } v; v.f = f;
    uint32_t u = v.u;
    return (unsigned short)((u + 0x7FFFu + ((u >> 16) & 1u)) >> 16);
}
__device__ __forceinline__ short8 gld_frag(const unsigned short* p) {
    union { uint4 u; short8 s; } t;
    t.u = *(const uint4*)p;            // 16B aligned
    return t.s;
}

// ---------------- kernel 1: fused softmax + filter/bias combine ----------------
// 256 blocks x 256 thr. Every block redundantly computes the [16][8] softmax
// (128 dots of length 64, L2-hot), then handles 256 (o,c) outputs of one batch.
// wfilt[b][t][o][c] = sum_n w[b][n] * filt_w[n][o][c][t]   (bf16)
// cbias[b][o]       = sum_n w[b][n] * filt_b[n][o]         (f32)
__global__ __launch_bounds__(256)
void k_prep(const float* __restrict__ cond,
            const float* __restrict__ sel_w,
            const float* __restrict__ sel_b,
            const float* __restrict__ filt_w,
            const float* __restrict__ filt_b,
            unsigned short* __restrict__ wfilt,
            float* __restrict__ cbias) {
    __shared__ float lg[BATCH][NBR];
    const int tid = threadIdx.x;
    if (tid < BATCH * NBR) {
        int b2 = tid >> 3, n = tid & 7;
        float acc = sel_b[n];
        #pragma unroll
        for (int c = 0; c < CIN; ++c)
            acc += cond[b2 * CIN + c] * sel_w[n * CIN + c];
        lg[b2][n] = acc;
    }
    __syncthreads();

    const int idx = blockIdx.x * 256 + tid;       // 65536 total
    const int b  = idx >> 12;                     // 0..15
    const int oc = idx & 4095;
    const int o  = oc >> 6, c = oc & 63;

    // local softmax for this b
    float w8[NBR];
    {
        float m = -1e30f;
        #pragma unroll
        for (int n = 0; n < NBR; ++n) m = fmaxf(m, lg[b][n]);
        float s = 0.f;
        #pragma unroll
        for (int n = 0; n < NBR; ++n) { w8[n] = __expf(lg[b][n] - m); s += w8[n]; }
        float inv = 1.f / s;
        #pragma unroll
        for (int n = 0; n < NBR; ++n) w8[n] *= inv;
    }

    float acc[9];
    #pragma unroll
    for (int t = 0; t < 9; ++t) acc[t] = 0.f;
    #pragma unroll
    for (int n = 0; n < NBR; ++n) {
        const float* p = filt_w + ((long)(n * COUT + o) * CIN + c) * 9;  // 9 contiguous floats
        #pragma unroll
        for (int t = 0; t < 9; ++t) acc[t] += w8[n] * p[t];
    }
    #pragma unroll
    for (int t = 0; t < 9; ++t)
        wfilt[((long)(b * 9 + t) * 4096) + oc] = f2bf(acc[t]);   // lanes c-fast: coalesced

    if (oc < COUT) {
        float ab = 0.f;
        #pragma unroll
        for (int n = 0; n < NBR; ++n) ab += w8[n] * filt_b[n * COUT + oc];
        cbias[b * COUT + oc] = ab;
    }
}

// ---------------- kernel 2: transpose NCHW f32 -> padded NHWC bf16 ----------------
// x_t[b][h'][w'][c], h',w' in [0,130); border = zeros. Thread <- one padded pixel.
__global__ __launch_bounds__(256)
void k_xpose(const float* __restrict__ x, unsigned short* __restrict__ x_t) {
    const int b = blockIdx.y;
    const int idx = blockIdx.x * 256 + threadIdx.x;
    if (idx >= HP * HP) return;
    const int h = idx / HP, w = idx % HP;
    const bool interior = (h >= 1) & (h <= HH) & (w >= 1) & (w <= WW);
    unsigned short* dst = x_t + ((long)(b * HP + h) * HP + w) * CIN;

    if (interior) {
        const float* src = x + ((long)b * CIN * HH + (h - 1)) * WW + (w - 1);
        #pragma unroll
        for (int half = 0; half < 2; ++half) {
            float v[32];
            #pragma unroll
            for (int c = 0; c < 32; ++c)
                v[c] = src[(long)(half * 32 + c) * HH * WW];   // lanes w-consecutive: coalesced
            uint4 q[4];
            #pragma unroll
            for (int j = 0; j < 4; ++j) {
                q[j].x = (unsigned)f2bf(v[8*j+0]) | ((unsigned)f2bf(v[8*j+1]) << 16);
                q[j].y = (unsigned)f2bf(v[8*j+2]) | ((unsigned)f2bf(v[8*j+3]) << 16);
                q[j].z = (unsigned)f2bf(v[8*j+4]) | ((unsigned)f2bf(v[8*j+5]) << 16);
                q[j].w = (unsigned)f2bf(v[8*j+6]) | ((unsigned)f2bf(v[8*j+7]) << 16);
            }
            #pragma unroll
            for (int j = 0; j < 4; ++j)
                ((uint4*)dst)[half * 4 + j] = q[j];
        }
    } else {
        uint4 z; z.x = z.y = z.z = z.w = 0;
        #pragma unroll
        for (int j = 0; j < 8; ++j) ((uint4*)dst)[j] = z;
    }
}

// ---------------- kernel 3: LDS-free implicit-GEMM conv ----------------
// block: batch b, 8 rows, 32 cols, 64 couts; 4 waves, wave = 2 rows.
// All operands via direct 16B global loads (x_t padded -> no masking).
// Bias folded into accumulator init. No LDS, no barriers.
__global__ __launch_bounds__(256)
void k_conv2(const unsigned short* __restrict__ x_t,
             const unsigned short* __restrict__ wfilt,
             const float* __restrict__ cbias,
             float* __restrict__ out) {
    const int b  = blockIdx.z;
    const int h0 = blockIdx.y * 8;
    const int w0 = blockIdx.x * 32;
    const int tid  = threadIdx.x;
    const int lane = tid & 63;
    const int wave = tid >> 6;
    const int l31  = lane & 31;
    const int lh   = lane >> 5;
    const int r0   = wave * 2;

    // bias-initialized accumulators (C/D row m = (i&3)+8*(i>>2)+4*lh)
    f32x16 acc00, acc01, acc10, acc11;
    #pragma unroll
    for (int i = 0; i < 16; ++i) {
        const int m = (i & 3) + 8 * (i >> 2) + 4 * lh;
        const float b0 = cbias[b * COUT + m];
        const float b1 = cbias[b * COUT + 32 + m];
        acc00[i] = b0; acc01[i] = b0;
        acc10[i] = b1; acc11[i] = b1;
    }

    const unsigned short* wf = wfilt + (long)b * 9 * COUT * CIN;
    const unsigned short* xb = x_t + (long)b * HP * HP * CIN;

    #pragma unroll
    for (int tap = 0; tap < 9; ++tap) {
        const int kh = tap / 3, kw = tap % 3;
        // padded coords: hin+1 = h0+r+kh, win+1 = w0+l31+kw
        const unsigned short* row0 = xb + ((long)(h0 + r0 + kh) * HP + (w0 + kw + l31)) * CIN;
        const unsigned short* row1 = row0 + (long)HP * CIN;
        const unsigned short* wft  = wf + (long)tap * COUT * CIN;
        #pragma unroll
        for (int cc = 0; cc < 4; ++cc) {
            const int kofs = cc * 16 + lh * 8;
            short8 a0 = gld_frag(wft + l31 * CIN + kofs);
            short8 a1 = gld_frag(wft + (32 + l31) * CIN + kofs);
            short8 b0 = gld_frag(row0 + kofs);
            short8 b1 = gld_frag(row1 + kofs);
            acc00 = __builtin_amdgcn_mfma_f32_32x32x16_bf16(a0, b0, acc00, 0, 0, 0);
            acc01 = __builtin_amdgcn_mfma_f32_32x32x16_bf16(a0, b1, acc01, 0, 0, 0);
            acc10 = __builtin_amdgcn_mfma_f32_32x32x16_bf16(a1, b0, acc10, 0, 0, 0);
            acc11 = __builtin_amdgcn_mfma_f32_32x32x16_bf16(a1, b1, acc11, 0, 0, 0);
        }
    }

    #pragma unroll
    for (int cb = 0; cb < 2; ++cb) {
        #pragma unroll
        for (int pb = 0; pb < 2; ++pb) {
            const f32x16 v = cb == 0 ? (pb == 0 ? acc00 : acc01)
                                     : (pb == 0 ? acc10 : acc11);
            const int hrow = h0 + r0 + pb;
            float* op = out + (((long)(b * COUT + cb * 32) * HH + hrow) * WW + w0 + l31);
            #pragma unroll
            for (int i = 0; i < 16; ++i) {
                const int m = (i & 3) + 8 * (i >> 2) + 4 * lh;
                op[(long)m * HH * WW] = v[i];
            }
        }
    }
}

// ---------------- fallback conv (round-1 LDS version) for small ws ----------------
#define RT 8
#define WT 32
#define SLABW 34
#define SLABR 10
#define PSTR  68

__device__ __forceinline__ short8 lds_frag(const unsigned short* p) {
    union { uint2 u[2]; short8 s; } t;
    t.u[0] = *(const uint2*)p;
    t.u[1] = *(const uint2*)(p + 4);
    return t.s;
}

__global__ __launch_bounds__(256)
void k_conv_fb(const float* __restrict__ x,
               const unsigned short* __restrict__ wfilt,
               const float* __restrict__ cbias,
               float* __restrict__ out) {
    __shared__ unsigned short lx[SLABR * SLABW * PSTR];
    __shared__ float lbias[COUT];

    const int b  = blockIdx.z;
    const int h0 = blockIdx.y * RT;
    const int w0 = blockIdx.x * WT;
    const int tid = threadIdx.x;

    if (tid < COUT) lbias[tid] = cbias[b * COUT + tid];

    const int NTASK = SLABR * SLABW * 8;
    for (int task = tid; task < NTASK; task += 256) {
        int wc  = task % SLABW;
        int pos = task / SLABW;
        int s   = pos % SLABR;
        int cg  = pos / SLABR;
        int hin = h0 + s - 1;
        int win = w0 + wc - 1;
        unsigned short v[8];
        if (hin >= 0 && hin < HH && win >= 0 && win < WW) {
            const float* px = x + (((long)(b * CIN + cg * 8) * HH + hin) * WW + win);
            #pragma unroll
            for (int j = 0; j < 8; ++j) v[j] = f2bf(px[(long)j * HH * WW]);
        } else {
            #pragma unroll
            for (int j = 0; j < 8; ++j) v[j] = 0;
        }
        int base = (s * SLABW + wc) * PSTR + cg * 8;
        uint2 lo, hi;
        lo.x = (unsigned)v[0] | ((unsigned)v[1] << 16);
        lo.y = (unsigned)v[2] | ((unsigned)v[3] << 16);
        hi.x = (unsigned)v[4] | ((unsigned)v[5] << 16);
        hi.y = (unsigned)v[6] | ((unsigned)v[7] << 16);
        *(uint2*)&lx[base]     = lo;
        *(uint2*)&lx[base + 4] = hi;
    }
    __syncthreads();

    const int lane = tid & 63;
    const int wave = tid >> 6;
    const int l31  = lane & 31;
    const int lh   = lane >> 5;
    const int r0   = wave * 2;

    f32x16 acc00, acc01, acc10, acc11;
    #pragma unroll
    for (int i = 0; i < 16; ++i) { acc00[i] = 0.f; acc01[i] = 0.f; acc10[i] = 0.f; acc11[i] = 0.f; }

    const unsigned short* wf = wfilt + (long)b * 9 * COUT * CIN;

    #pragma unroll
    for (int tap = 0; tap < 9; ++tap) {
        const int kh = tap / 3, kw = tap % 3;
        const unsigned short* wft = wf + (long)tap * COUT * CIN;
        #pragma unroll
        for (int cc = 0; cc < 4; ++cc) {
            const int kofs = cc * 16 + lh * 8;
            short8 a0 = gld_frag(wft + (l31)      * CIN + kofs);
            short8 a1 = gld_frag(wft + (32 + l31) * CIN + kofs);
            short8 b0 = lds_frag(&lx[((r0     + kh) * SLABW + l31 + kw) * PSTR + kofs]);
            short8 b1 = lds_frag(&lx[((r0 + 1 + kh) * SLABW + l31 + kw) * PSTR + kofs]);
            acc00 = __builtin_amdgcn_mfma_f32_32x32x16_bf16(a0, b0, acc00, 0, 0, 0);
            acc01 = __builtin_amdgcn_mfma_f32_32x32x16_bf16(a0, b1, acc01, 0, 0, 0);
            acc10 = __builtin_amdgcn_mfma_f32_32x32x16_bf16(a1, b0, acc10, 0, 0, 0);
            acc11 = __builtin_amdgcn_mfma_f32_32x32x16_bf16(a1, b1, acc11, 0, 0, 0);
        }
    }

    #pragma unroll
    for (int cb = 0; cb < 2; ++cb) {
        #pragma unroll
        for (int pb = 0; pb < 2; ++pb) {
            const f32x16 v = cb == 0 ? (pb == 0 ? acc00 : acc01)
                                     : (pb == 0 ? acc10 : acc11);
            const int hrow = h0 + r0 + pb;
            float* op = out + (((long)(b * COUT + cb * 32) * HH + hrow) * WW + w0 + l31);
            #pragma unroll
            for (int i = 0; i < 16; ++i) {
                int m = (i & 3) + 8 * (i >> 2) + 4 * lh;
                op[(long)m * HH * WW] = v[i] + lbias[cb * 32 + m];
            }
        }
    }
}

extern "C" void kernel_launch(void* const* d_in, const int* in_sizes, int n_in,
                              void* d_out, int out_size, void* d_ws, size_t ws_size,
                              hipStream_t stream) {
    const float* x      = (const float*)d_in[0];
    const float* cond   = (const float*)d_in[1];
    const float* filt_w = (const float*)d_in[2];
    const float* filt_b = (const float*)d_in[3];
    const float* sel_w  = (const float*)d_in[4];
    const float* sel_b  = (const float*)d_in[5];
    float* out = (float*)d_out;

    // ws layout: cbias [16][64] f32 @0; wfilt [16][9][64][64] bf16 @4096;
    //            x_t [16][130][130][64] bf16 @1183744 (fast path only)
    float*          cbias = (float*)d_ws;
    unsigned short* wfilt = (unsigned short*)((char*)d_ws + 4096);
    unsigned short* x_t   = (unsigned short*)((char*)d_ws + 1183744);
    const size_t need = 1183744ull + (size_t)BATCH * HP * HP * CIN * 2ull;

    k_prep<<<256, 256, 0, stream>>>(cond, sel_w, sel_b, filt_w, filt_b, wfilt, cbias);

    if (ws_size >= need) {
        dim3 gx((HP * HP + 255) / 256, BATCH);           // 67 x 16
        k_xpose<<<gx, 256, 0, stream>>>(x, x_t);
        dim3 grid(WW / 32, HH / 8, BATCH);               // 4 x 16 x 16
        k_conv2<<<grid, 256, 0, stream>>>(x_t, wfilt, cbias, out);
    } else {
        dim3 grid(WW / WT, HH / RT, BATCH);
        k_conv_fb<<<grid, 256, 0, stream>>>(x, wfilt, cbias, out);
    }
}

// Round 3
// 192.219 us; speedup vs baseline: 1.0962x; 1.0962x over previous
//
#include <hip/hip_runtime.h>
#include <stdint.h>

#define BATCH 16
#define CIN   64
#define COUT  64
#define NBR   8
#define HH    128
#define WW    128

typedef __attribute__((ext_vector_type(8)))  short short8;
typedef __attribute__((ext_vector_type(16))) float f32x16;

// round-half-up f32->bf16 (1 add + shift; inputs are tame normals, no NaN/inf)
__device__ __forceinline__ unsigned int f2bf_hi(float f) {
    union { float f; uint32_t u; } v; v.f = f;
    return (v.u + 0x8000u) >> 16;
}
// RNE version (used in k_prep where it's cheap)
__device__ __forceinline__ unsigned short f2bf(float f) {
    union { float f; uint32_t u; } v; v.f = f;
    uint32_t u = v.u;
    return (unsigned short)((u + 0x7FFFu + ((u >> 16) & 1u)) >> 16);
}
__device__ __forceinline__ short8 gld_frag(const unsigned short* p) {
    union { uint4 u; short8 s; } t;
    t.u = *(const uint4*)p;            // 16B aligned
    return t.s;
}
__device__ __forceinline__ short8 lds_frag(const unsigned short* p) {
    union { uint2 u[2]; short8 s; } t;
    t.u[0] = *(const uint2*)p;         // 8B aligned
    t.u[1] = *(const uint2*)(p + 4);
    return t.s;
}

// ---------------- kernel 1: fused softmax + filter/bias combine ----------------
// wfilt[b][t][o][c] = sum_n w[b][n] * filt_w[n][o][c][t]   (bf16)
// cbias[b][o]       = sum_n w[b][n] * filt_b[n][o]         (f32)
__global__ __launch_bounds__(256)
void k_prep(const float* __restrict__ cond,
            const float* __restrict__ sel_w,
            const float* __restrict__ sel_b,
            const float* __restrict__ filt_w,
            const float* __restrict__ filt_b,
            unsigned short* __restrict__ wfilt,
            float* __restrict__ cbias) {
    __shared__ float lg[BATCH][NBR];
    const int tid = threadIdx.x;
    if (tid < BATCH * NBR) {
        int b2 = tid >> 3, n = tid & 7;
        float acc = sel_b[n];
        #pragma unroll
        for (int c = 0; c < CIN; ++c)
            acc += cond[b2 * CIN + c] * sel_w[n * CIN + c];
        lg[b2][n] = acc;
    }
    __syncthreads();

    const int idx = blockIdx.x * 256 + tid;       // 65536 total
    const int b  = idx >> 12;
    const int oc = idx & 4095;
    const int o  = oc >> 6, c = oc & 63;

    float w8[NBR];
    {
        float m = -1e30f;
        #pragma unroll
        for (int n = 0; n < NBR; ++n) m = fmaxf(m, lg[b][n]);
        float s = 0.f;
        #pragma unroll
        for (int n = 0; n < NBR; ++n) { w8[n] = __expf(lg[b][n] - m); s += w8[n]; }
        float inv = 1.f / s;
        #pragma unroll
        for (int n = 0; n < NBR; ++n) w8[n] *= inv;
    }

    float acc[9];
    #pragma unroll
    for (int t = 0; t < 9; ++t) acc[t] = 0.f;
    #pragma unroll
    for (int n = 0; n < NBR; ++n) {
        const float* p = filt_w + ((long)(n * COUT + o) * CIN + c) * 9;
        #pragma unroll
        for (int t = 0; t < 9; ++t) acc[t] += w8[n] * p[t];
    }
    #pragma unroll
    for (int t = 0; t < 9; ++t)
        wfilt[((long)(b * 9 + t) * 4096) + oc] = f2bf(acc[t]);

    if (oc < COUT) {
        float ab = 0.f;
        #pragma unroll
        for (int n = 0; n < NBR; ++n) ab += w8[n] * filt_b[n * COUT + oc];
        cbias[b * COUT + oc] = ab;
    }
}

// ---------------- kernel 2: fused implicit-GEMM conv with vectorized staging ----------------
#define RT 8
#define WT 32
#define SLABW 34          // WT + 2 halo
#define SLABR 10          // RT + 2 halo
#define PSTR  68          // ushorts per pixel (64 ch + 4 pad)

__global__ __launch_bounds__(256, 3)
void k_conv3(const float* __restrict__ x,
             const unsigned short* __restrict__ wfilt,
             const float* __restrict__ cbias,
             float* __restrict__ out) {
    __shared__ unsigned short lx[SLABR * SLABW * PSTR];   // 46240 B

    const int b  = blockIdx.z;
    const int h0 = blockIdx.y * RT;
    const int w0 = blockIdx.x * WT;
    const int tid = threadIdx.x;

    // ---- stage x slab: task = (s, channel-pair cp, j). one float4 per channel,
    // pack (c,c+1) per pixel -> dword -> ds_write_b32. 3200 tasks, 12.5/thread.
    for (int task = tid; task < SLABR * 32 * 10; task += 256) {
        const int j  = task % 10;
        const int r  = task / 10;
        const int cp = r & 31;
        const int s  = r >> 5;
        const int c  = cp * 2;
        const int hin   = h0 + s - 1;
        const int wbase = w0 - 4 + j * 4;          // multiple of 4 -> float4 all-in or all-out
        float4 v0, v1;
        v0.x = v0.y = v0.z = v0.w = 0.f;
        v1 = v0;
        if (hin >= 0 && hin < HH && wbase >= 0 && wbase < WW) {
            const float* px = x + (((long)(b * CIN + c) * HH + hin) * WW + wbase);
            v0 = *(const float4*)px;
            v1 = *(const float4*)(px + (long)HH * WW);
        }
        unsigned int d[4];
        d[0] = f2bf_hi(v0.x) | (f2bf_hi(v1.x) << 16);
        d[1] = f2bf_hi(v0.y) | (f2bf_hi(v1.y) << 16);
        d[2] = f2bf_hi(v0.z) | (f2bf_hi(v1.z) << 16);
        d[3] = f2bf_hi(v0.w) | (f2bf_hi(v1.w) << 16);
        #pragma unroll
        for (int i = 0; i < 4; ++i) {
            const int p = j * 4 - 3 + i;           // slab pixel in [-3, 37)
            if (p >= 0 && p < SLABW)
                *(unsigned int*)&lx[(s * SLABW + p) * PSTR + c] = d[i];
        }
    }

    const int lane = tid & 63;
    const int wave = tid >> 6;
    const int l31  = lane & 31;
    const int lh   = lane >> 5;
    const int r0   = wave * 2;

    // bias-initialized accumulators (C/D row m = (i&3)+8*(i>>2)+4*lh)
    f32x16 acc00, acc01, acc10, acc11;
    #pragma unroll
    for (int i = 0; i < 16; ++i) {
        const int m = (i & 3) + 8 * (i >> 2) + 4 * lh;
        const float b0 = cbias[b * COUT + m];
        const float b1 = cbias[b * COUT + 32 + m];
        acc00[i] = b0; acc01[i] = b0;
        acc10[i] = b1; acc11[i] = b1;
    }

    __syncthreads();

    const unsigned short* wf = wfilt + (long)b * 9 * COUT * CIN;

    #pragma unroll
    for (int tap = 0; tap < 9; ++tap) {
        const int kh = tap / 3, kw = tap % 3;
        const unsigned short* wft = wf + (long)tap * COUT * CIN;
        #pragma unroll
        for (int cc = 0; cc < 4; ++cc) {
            const int kofs = cc * 16 + lh * 8;
            short8 a0 = gld_frag(wft + l31 * CIN + kofs);
            short8 a1 = gld_frag(wft + (32 + l31) * CIN + kofs);
            short8 b0 = lds_frag(&lx[((r0     + kh) * SLABW + l31 + kw) * PSTR + kofs]);
            short8 b1 = lds_frag(&lx[((r0 + 1 + kh) * SLABW + l31 + kw) * PSTR + kofs]);
            acc00 = __builtin_amdgcn_mfma_f32_32x32x16_bf16(a0, b0, acc00, 0, 0, 0);
            acc01 = __builtin_amdgcn_mfma_f32_32x32x16_bf16(a0, b1, acc01, 0, 0, 0);
            acc10 = __builtin_amdgcn_mfma_f32_32x32x16_bf16(a1, b0, acc10, 0, 0, 0);
            acc11 = __builtin_amdgcn_mfma_f32_32x32x16_bf16(a1, b1, acc11, 0, 0, 0);
        }
    }

    #pragma unroll
    for (int cb = 0; cb < 2; ++cb) {
        #pragma unroll
        for (int pb = 0; pb < 2; ++pb) {
            const f32x16 v = cb == 0 ? (pb == 0 ? acc00 : acc01)
                                     : (pb == 0 ? acc10 : acc11);
            const int hrow = h0 + r0 + pb;
            float* op = out + (((long)(b * COUT + cb * 32) * HH + hrow) * WW + w0 + l31);
            #pragma unroll
            for (int i = 0; i < 16; ++i) {
                const int m = (i & 3) + 8 * (i >> 2) + 4 * lh;
                op[(long)m * HH * WW] = v[i];
            }
        }
    }
}

extern "C" void kernel_launch(void* const* d_in, const int* in_sizes, int n_in,
                              void* d_out, int out_size, void* d_ws, size_t ws_size,
                              hipStream_t stream) {
    const float* x      = (const float*)d_in[0];
    const float* cond   = (const float*)d_in[1];
    const float* filt_w = (const float*)d_in[2];
    const float* filt_b = (const float*)d_in[3];
    const float* sel_w  = (const float*)d_in[4];
    const float* sel_b  = (const float*)d_in[5];
    float* out = (float*)d_out;

    // ws: cbias [16][64] f32 @0; wfilt [16][9][64][64] bf16 @4096  (1.13 MB total)
    float*          cbias = (float*)d_ws;
    unsigned short* wfilt = (unsigned short*)((char*)d_ws + 4096);

    k_prep<<<256, 256, 0, stream>>>(cond, sel_w, sel_b, filt_w, filt_b, wfilt, cbias);

    dim3 grid(WW / WT, HH / RT, BATCH);                  // 4 x 16 x 16 = 1024 blocks
    k_conv3<<<grid, 256, 0, stream>>>(x, wfilt, cbias, out);
}

// Round 4
// 176.878 us; speedup vs baseline: 1.1913x; 1.0867x over previous
//
#include <hip/hip_runtime.h>
#include <stdint.h>

#define BATCH 16
#define CIN   64
#define COUT  64
#define NBR   8
#define HH    128
#define WW    128

typedef __attribute__((ext_vector_type(8)))  short short8;
typedef __attribute__((ext_vector_type(16))) float f32x16;

// round-half-up f32->bf16 (inputs are tame normals; 3.4x error headroom measured)
__device__ __forceinline__ unsigned int f2bf_hi(float f) {
    union { float f; uint32_t u; } v; v.f = f;
    return (v.u + 0x8000u) >> 16;
}
// RNE version
__device__ __forceinline__ unsigned short f2bf(float f) {
    union { float f; uint32_t u; } v; v.f = f;
    uint32_t u = v.u;
    return (unsigned short)((u + 0x7FFFu + ((u >> 16) & 1u)) >> 16);
}
__device__ __forceinline__ short8 gld_frag(const unsigned short* p) {
    union { uint4 u; short8 s; } t;
    t.u = *(const uint4*)p;            // 16B aligned
    return t.s;
}
__device__ __forceinline__ short8 lds_frag(const unsigned short* p) {
    union { uint2 u[2]; short8 s; } t;
    t.u[0] = *(const uint2*)p;         // 8B aligned
    t.u[1] = *(const uint2*)(p + 4);
    return t.s;
}

// ---------------- kernel 1: softmax + filter/bias combine (1024 blocks) ----------------
// block = (b, o). Stages filt_w[n][o][:][:] (8 x 576 f32, contiguous) to LDS via
// coalesced float4; logits via wave shfl-reduce; writes wfilt[b][t][o][c] coalesced.
__global__ __launch_bounds__(256)
void k_prep(const float* __restrict__ cond,
            const float* __restrict__ sel_w,
            const float* __restrict__ sel_b,
            const float* __restrict__ filt_w,
            const float* __restrict__ filt_b,
            unsigned short* __restrict__ wfilt,
            float* __restrict__ cbias) {
    __shared__ float4 lw4[NBR * 144];          // 8 x 576 floats = 18432 B
    __shared__ float lg[NBR];
    float* lw = (float*)lw4;

    const int blk = blockIdx.x;                // 1024
    const int b = blk >> 6, o = blk & 63;
    const int tid = threadIdx.x;

    // stage filter rows: src offset for (n,o) = (n*64+o)*144 float4s, contiguous
    const float4* src4 = (const float4*)filt_w;
    #pragma unroll
    for (int i = tid; i < NBR * 144; i += 256)
        lw4[i] = src4[((i / 144) * COUT + o) * 144 + (i % 144)];

    // logits: wave w computes n = w and n = w+4 via 64-lane shfl reduction
    {
        const int lane = tid & 63, w = tid >> 6;
        const float c0 = cond[b * CIN + lane];
        #pragma unroll
        for (int k = 0; k < 2; ++k) {
            const int n = w + k * 4;
            float p = c0 * sel_w[n * CIN + lane];
            #pragma unroll
            for (int off = 32; off > 0; off >>= 1)
                p += __shfl_down(p, off, 64);
            if (lane == 0) lg[n] = p + sel_b[n];
        }
    }
    __syncthreads();

    float w8[NBR];
    {
        float m = -1e30f;
        #pragma unroll
        for (int n = 0; n < NBR; ++n) m = fmaxf(m, lg[n]);
        float s = 0.f;
        #pragma unroll
        for (int n = 0; n < NBR; ++n) { w8[n] = __expf(lg[n] - m); s += w8[n]; }
        const float inv = 1.f / s;
        #pragma unroll
        for (int n = 0; n < NBR; ++n) w8[n] *= inv;
    }

    // outputs: idx = t*64 + c; LDS read stride 9 dwords (gcd(9,32)=1 -> 2-way, free)
    #pragma unroll
    for (int idx = tid; idx < 576; idx += 256) {
        const int t = idx >> 6, c = idx & 63;
        float acc = 0.f;
        #pragma unroll
        for (int n = 0; n < NBR; ++n)
            acc += w8[n] * lw[n * 576 + c * 9 + t];
        wfilt[(((long)(b * 9 + t) * COUT + o) << 6) + c] = f2bf(acc);
    }
    if (tid == 0) {
        float ab = 0.f;
        #pragma unroll
        for (int n = 0; n < NBR; ++n) ab += w8[n] * filt_b[n * COUT + o];
        cbias[b * COUT + o] = ab;
    }
}

// ---------------- kernel 2: fused conv, tap-granularity A prefetch ----------------
#define RT 8
#define WT 32
#define SLABW 34          // WT + 2 halo
#define SLABR 10          // RT + 2 halo
#define PSTR  68          // ushorts per pixel (64 ch + 4 pad; b64 reads are 2-way/free)

__global__ __launch_bounds__(256, 2)
void k_conv4(const float* __restrict__ x,
             const unsigned short* __restrict__ wfilt,
             const float* __restrict__ cbias,
             float* __restrict__ out) {
    __shared__ unsigned short lx[SLABR * SLABW * PSTR];   // 46240 B

    const int b  = blockIdx.z;
    const int h0 = blockIdx.y * RT;
    const int w0 = blockIdx.x * WT;
    const int tid = threadIdx.x;

    // ---- stage x slab: task = (s, channel-pair, j); float4 per channel ----
    for (int task = tid; task < SLABR * 32 * 10; task += 256) {
        const int j  = task % 10;
        const int r  = task / 10;
        const int cp = r & 31;
        const int s  = r >> 5;
        const int c  = cp * 2;
        const int hin   = h0 + s - 1;
        const int wbase = w0 - 4 + j * 4;
        float4 v0, v1;
        v0.x = v0.y = v0.z = v0.w = 0.f;
        v1 = v0;
        if (hin >= 0 && hin < HH && wbase >= 0 && wbase < WW) {
            const float* px = x + (((long)(b * CIN + c) * HH + hin) * WW + wbase);
            v0 = *(const float4*)px;
            v1 = *(const float4*)(px + (long)HH * WW);
        }
        unsigned int d[4];
        d[0] = f2bf_hi(v0.x) | (f2bf_hi(v1.x) << 16);
        d[1] = f2bf_hi(v0.y) | (f2bf_hi(v1.y) << 16);
        d[2] = f2bf_hi(v0.z) | (f2bf_hi(v1.z) << 16);
        d[3] = f2bf_hi(v0.w) | (f2bf_hi(v1.w) << 16);
        #pragma unroll
        for (int i = 0; i < 4; ++i) {
            const int p = j * 4 - 3 + i;
            if (p >= 0 && p < SLABW)
                *(unsigned int*)&lx[(s * SLABW + p) * PSTR + c] = d[i];
        }
    }

    const int lane = tid & 63;
    const int wave = tid >> 6;
    const int l31  = lane & 31;
    const int lh   = lane >> 5;
    const int r0   = wave * 2;

    const unsigned short* wf = wfilt + (long)b * 9 * COUT * CIN;

    // prefetch tap-0 A fragments (independent of LDS staging -> overlaps it)
    short8 A0[4], A1[4];
    #pragma unroll
    for (int cc = 0; cc < 4; ++cc) {
        A0[cc] = gld_frag(wf + l31 * CIN + cc * 16 + lh * 8);
        A1[cc] = gld_frag(wf + (32 + l31) * CIN + cc * 16 + lh * 8);
    }

    // bias-initialized accumulators (C/D row m = (i&3)+8*(i>>2)+4*lh)
    f32x16 acc00, acc01, acc10, acc11;
    #pragma unroll
    for (int i = 0; i < 16; ++i) {
        const int m = (i & 3) + 8 * (i >> 2) + 4 * lh;
        const float b0 = cbias[b * COUT + m];
        const float b1 = cbias[b * COUT + 32 + m];
        acc00[i] = b0; acc01[i] = b0;
        acc10[i] = b1; acc11[i] = b1;
    }

    __syncthreads();

    #pragma unroll
    for (int tap = 0; tap < 9; ++tap) {
        // prefetch next tap's A into fresh registers BEFORE this tap's MFMAs
        short8 nA0[4], nA1[4];
        if (tap < 8) {
            const unsigned short* wn = wf + (long)(tap + 1) * COUT * CIN;
            #pragma unroll
            for (int cc = 0; cc < 4; ++cc) {
                nA0[cc] = gld_frag(wn + l31 * CIN + cc * 16 + lh * 8);
                nA1[cc] = gld_frag(wn + (32 + l31) * CIN + cc * 16 + lh * 8);
            }
        }
        const int kh = tap / 3, kw = tap % 3;
        #pragma unroll
        for (int cc = 0; cc < 4; ++cc) {
            const int kofs = cc * 16 + lh * 8;
            short8 b0 = lds_frag(&lx[((r0     + kh) * SLABW + l31 + kw) * PSTR + kofs]);
            short8 b1 = lds_frag(&lx[((r0 + 1 + kh) * SLABW + l31 + kw) * PSTR + kofs]);
            acc00 = __builtin_amdgcn_mfma_f32_32x32x16_bf16(A0[cc], b0, acc00, 0, 0, 0);
            acc01 = __builtin_amdgcn_mfma_f32_32x32x16_bf16(A0[cc], b1, acc01, 0, 0, 0);
            acc10 = __builtin_amdgcn_mfma_f32_32x32x16_bf16(A1[cc], b0, acc10, 0, 0, 0);
            acc11 = __builtin_amdgcn_mfma_f32_32x32x16_bf16(A1[cc], b1, acc11, 0, 0, 0);
        }
        #pragma unroll
        for (int cc = 0; cc < 4; ++cc) { A0[cc] = nA0[cc]; A1[cc] = nA1[cc]; }
    }

    #pragma unroll
    for (int cb = 0; cb < 2; ++cb) {
        #pragma unroll
        for (int pb = 0; pb < 2; ++pb) {
            const f32x16 v = cb == 0 ? (pb == 0 ? acc00 : acc01)
                                     : (pb == 0 ? acc10 : acc11);
            const int hrow = h0 + r0 + pb;
            float* op = out + (((long)(b * COUT + cb * 32) * HH + hrow) * WW + w0 + l31);
            #pragma unroll
            for (int i = 0; i < 16; ++i) {
                const int m = (i & 3) + 8 * (i >> 2) + 4 * lh;
                op[(long)m * HH * WW] = v[i];
            }
        }
    }
}

extern "C" void kernel_launch(void* const* d_in, const int* in_sizes, int n_in,
                              void* d_out, int out_size, void* d_ws, size_t ws_size,
                              hipStream_t stream) {
    const float* x      = (const float*)d_in[0];
    const float* cond   = (const float*)d_in[1];
    const float* filt_w = (const float*)d_in[2];
    const float* filt_b = (const float*)d_in[3];
    const float* sel_w  = (const float*)d_in[4];
    const float* sel_b  = (const float*)d_in[5];
    float* out = (float*)d_out;

    // ws: cbias [16][64] f32 @0; wfilt [16][9][64][64] bf16 @4096
    float*          cbias = (float*)d_ws;
    unsigned short* wfilt = (unsigned short*)((char*)d_ws + 4096);

    k_prep<<<BATCH * COUT, 256, 0, stream>>>(cond, sel_w, sel_b, filt_w, filt_b, wfilt, cbias);

    dim3 grid(WW / WT, HH / RT, BATCH);                  // 4 x 16 x 16 = 1024 blocks
    k_conv4<<<grid, 256, 0, stream>>>(x, wfilt, cbias, out);
}